// Round 5
// baseline (415.077 us; speedup 1.0000x reference)
//
#include <hip/hip_runtime.h>
#include <math.h>

// Problem constants (B=2,S=2048 -> T=4096; D=H=1024; E=16; K=2; CF=1.25)
#define T_TOK 4096
#define DIM   1024
#define HID   1024
#define NE    16
#define CAP   640      // ceil(T*K/E*CF)
#define CBUF  1280     // K*CAP
#define BM 128
#define BN 128
#define BK 32
#define MAXTILE 160    // NE * (CBUF/BM) upper bound on active m-tiles

typedef __attribute__((ext_vector_type(8))) short short8;   // 8 bf16 (4 VGPRs)
typedef __attribute__((ext_vector_type(4))) float f32x4;    // MFMA accumulator

static __device__ __forceinline__ unsigned short f2bf(float f) {
    unsigned int u = __float_as_uint(f);
    u += 0x7fff + ((u >> 16) & 1);   // RNE
    return (unsigned short)(u >> 16);
}

// async global->LDS DMA, 16B per lane; dst is wave-uniform base, lane i lands
// at dst + i*16. Source chunks are XOR-swizzled (chunk c of row r at c^((r>>1)&3))
// so the unpadded 64B-row LDS layout reads conflict-free with ds_read_b128.
static __device__ __forceinline__ void async16(const void* g, void* l) {
    __builtin_amdgcn_global_load_lds((const __attribute__((address_space(1))) void*)g,
                                     (__attribute__((address_space(3))) void*)l, 16, 0, 0);
}

// ---------------- x -> bf16 (with zero padding row at index T) ----------------
__global__ void convert_x_k(const float* __restrict__ x, unsigned short* __restrict__ xb) {
    int i = blockIdx.x * blockDim.x + threadIdx.x;
    int base = i * 4;
    int row = base >> 10;
    ushort4 o;
    if (row < T_TOK) {
        float4 v = *(const float4*)(x + base);
        o.x = f2bf(v.x); o.y = f2bf(v.y); o.z = f2bf(v.z); o.w = f2bf(v.w);
    } else {
        o.x = 0; o.y = 0; o.z = 0; o.w = 0;
    }
    *(ushort4*)(xb + base) = o;
}

// ------------- fused weight transpose: fp32 [e][k][n] -> bf16 [e][n][k] -------------
// 64x64 tiles. Reads: 16 lanes x 16B = 256B/row segments. Writes: 8 lanes x 16B
// = full 128B output rows (was 16B-with-holes -> 2.3 TB/s). LDS stride 66 elems
// (33 dwords): b32 read phase banks = (33n+4j+c)%32, <=2-way (free, m136).
#define TSP 66
__global__ void transpose_cvt_k(const float* __restrict__ W0, const float* __restrict__ W1,
                                const float* __restrict__ W2,
                                unsigned short* __restrict__ T0, unsigned short* __restrict__ T1,
                                unsigned short* __restrict__ T2) {
    __shared__ unsigned short s[64 * TSP];
    int zz = blockIdx.z;                 // 0..47
    int which = zz >> 4, e = zz & 15;
    const float* W = (which == 0) ? W0 : (which == 1) ? W1 : W2;
    unsigned short* T = (which == 0) ? T0 : (which == 1) ? T1 : T2;
    const float* Wp = W + (size_t)e * DIM * HID;
    unsigned short* Tp = T + (size_t)e * DIM * HID;
    int k0 = blockIdx.y * 64, n0 = blockIdx.x * 64;
    int tid = threadIdx.x;
    int tx = tid & 15, ty = tid >> 4;
    #pragma unroll
    for (int i = 0; i < 4; ++i) {
        int k = ty + i * 16;
        float4 v = *(const float4*)(Wp + (size_t)(k0 + k) * 1024 + n0 + tx * 4);
        int nb = tx * 4;
        s[(nb + 0) * TSP + k] = f2bf(v.x);
        s[(nb + 1) * TSP + k] = f2bf(v.y);
        s[(nb + 2) * TSP + k] = f2bf(v.z);
        s[(nb + 3) * TSP + k] = f2bf(v.w);
    }
    __syncthreads();
    int j = tid & 7, kseg = j * 8;        // 16B segment of the output row
    int nb2 = tid >> 3;                   // 0..31
    #pragma unroll
    for (int h = 0; h < 2; ++h) {
        int n = h * 32 + nb2;
        uint4 o;
        o.x = *(const unsigned int*)&s[n * TSP + kseg + 0];
        o.y = *(const unsigned int*)&s[n * TSP + kseg + 2];
        o.z = *(const unsigned int*)&s[n * TSP + kseg + 4];
        o.w = *(const unsigned int*)&s[n * TSP + kseg + 6];
        *(uint4*)(Tp + (size_t)(n0 + n) * 1024 + k0 + kseg) = o;
    }
}

// ---------------- router: logits, softmax, top-2 (one wave per token) ----------------
__global__ void router_k(const float* __restrict__ x, const float* __restrict__ rw,
                         int* __restrict__ route_e, float* __restrict__ route_w) {
    int t = blockIdx.x;
    int lane = threadIdx.x;
    const float* xr = x + (size_t)t * DIM + lane * 16;
    float4 xv0 = *(const float4*)(xr + 0);
    float4 xv1 = *(const float4*)(xr + 4);
    float4 xv2 = *(const float4*)(xr + 8);
    float4 xv3 = *(const float4*)(xr + 12);
    float xl[16] = {xv0.x, xv0.y, xv0.z, xv0.w, xv1.x, xv1.y, xv1.z, xv1.w,
                    xv2.x, xv2.y, xv2.z, xv2.w, xv3.x, xv3.y, xv3.z, xv3.w};
    float p[16];
    #pragma unroll
    for (int e = 0; e < 16; ++e) p[e] = 0.f;
    #pragma unroll
    for (int j = 0; j < 16; ++j) {
        const float4* rp = (const float4*)(rw + (size_t)(lane * 16 + j) * 16);
        float4 r0 = rp[0], r1 = rp[1], r2 = rp[2], r3 = rp[3];
        float xv = xl[j];
        p[0]  += xv * r0.x; p[1]  += xv * r0.y; p[2]  += xv * r0.z; p[3]  += xv * r0.w;
        p[4]  += xv * r1.x; p[5]  += xv * r1.y; p[6]  += xv * r1.z; p[7]  += xv * r1.w;
        p[8]  += xv * r2.x; p[9]  += xv * r2.y; p[10] += xv * r2.z; p[11] += xv * r2.w;
        p[12] += xv * r3.x; p[13] += xv * r3.y; p[14] += xv * r3.z; p[15] += xv * r3.w;
    }
    #pragma unroll
    for (int off = 32; off > 0; off >>= 1) {
        #pragma unroll
        for (int e = 0; e < 16; ++e) p[e] += __shfl_xor(p[e], off);
    }
    if (lane == 0) {
        float m = p[0];
        #pragma unroll
        for (int e = 1; e < 16; ++e) m = fmaxf(m, p[e]);
        float s = 0.f;
        #pragma unroll
        for (int e = 0; e < 16; ++e) s = s + __expf(p[e] - m);
        float v0 = -1e30f, v1 = -1e30f; int i0 = 0, i1 = 0;
        #pragma unroll
        for (int e = 0; e < 16; ++e) {
            float v = p[e];
            if (v > v0)      { v1 = v0; i1 = i0; v0 = v; i0 = e; }
            else if (v > v1) { v1 = v;  i1 = e; }
        }
        route_e[t*2+0] = i0;  route_e[t*2+1] = i1;
        route_w[t*2+0] = __expf(v0 - m) / s;
        route_w[t*2+1] = __expf(v1 - m) / s;
    }
}

// ------- dispatch build: ballot rank/slot + inverse map smap + tile list -------
__global__ __launch_bounds__(1024)
void build_dispatch_k(const int* __restrict__ route_e, const float* __restrict__ route_w,
                      int* __restrict__ disp, int* __restrict__ smap, int* __restrict__ tmeta) {
    __shared__ unsigned char eidx[2 * T_TOK];
    __shared__ unsigned char keepf[2 * T_TOK];
    __shared__ int totals[NE];
    int tid = threadIdx.x;
    int wv = tid >> 6, lane = tid & 63;

    {   // route_e (8192 ints) -> bytes, coalesced
        int4 a = ((const int4*)route_e)[tid * 2];
        int4 b = ((const int4*)route_e)[tid * 2 + 1];
        unsigned int lo = (a.x & 0xff) | ((a.y & 0xff) << 8) | ((a.z & 0xff) << 16) | ((a.w & 0xff) << 24);
        unsigned int hi = (b.x & 0xff) | ((b.y & 0xff) << 8) | ((b.z & 0xff) << 16) | ((b.w & 0xff) << 24);
        uint2 pk; pk.x = lo; pk.y = hi;
        *(uint2*)(eidx + tid * 8) = pk;
    }
    for (int i = tid; i < 2 * T_TOK; i += 1024) smap[i] = -1;   // default: dropped
    __syncthreads();

    unsigned long long below = (lane == 0) ? 0ull : ((~0ull) >> (64 - lane));
    #pragma unroll
    for (int s = 0; s < 2; ++s) {      // keep = token-order rank in (e,k) stream < CAP
        int st = wv + s * 16;
        int e = st >> 1, k = st & 1;
        int run = 0;
        for (int base = 0; base < T_TOK; base += 64) {
            int t = base + lane;
            int hit = (eidx[t * 2 + k] == e);
            unsigned long long m = __ballot(hit);
            int rank = run + __popcll(m & below);
            if (hit) keepf[t * 2 + k] = (rank < CAP) ? 1 : 0;
            run += __popcll(m);
        }
    }
    __syncthreads();

    {   // slot = flat-order rank among kept entries of expert e (one wave per expert)
        int e = wv;
        int run = 0;
        for (int base = 0; base < 2 * T_TOK; base += 64) {
            int f = base + lane;
            int hit = (eidx[f] == e) && keepf[f];
            unsigned long long m = __ballot(hit);
            int slot = run + __popcll(m & below);
            if (hit) {
                disp[e * CBUF + slot] = f >> 1;
                smap[f] = e * CBUF + slot;
            }
            run += __popcll(m);
        }
        if (lane == 0) totals[e] = run;
    }
    __syncthreads();

    for (int i = tid; i < NE * CBUF; i += 1024) {   // pad unused slots -> zero row
        int e = i / CBUF, s = i - e * CBUF;
        if (s >= totals[e]) disp[i] = T_TOK;
    }

    if (tid == 0) {   // active-tile list
        int n = 0;
        for (int e = 0; e < NE; ++e) {
            int ntl = (totals[e] + BM - 1) / BM;
            for (int m = 0; m < ntl; ++m) { tmeta[4 + n] = (e << 8) | m; ++n; }
        }
        tmeta[0] = n;
    }
}

// ---------------- GEMM1: xe @ {gate,up} fused + SiLU -> hidden (bf16) ----------------
// 2-stage double-buffered global_load_lds pipeline (3 arrays x 3 stages would
// exceed the 64KB static LDS limit; gemm2 runs the 3-stage variant as A/B).
__global__ __launch_bounds__(256, 2)
void gemm1_k(const unsigned short* __restrict__ xb, const unsigned short* __restrict__ gt,
             const unsigned short* __restrict__ ut, const int* __restrict__ disp,
             const int* __restrict__ tmeta, unsigned short* __restrict__ hidden) {
    int slot = blockIdx.y;
    if (slot >= tmeta[0]) return;
    int pk = tmeta[4 + slot];
    int e = pk >> 8, mt = pk & 255;
    int m0 = mt * BM, n0 = blockIdx.x * BN;

    __shared__ unsigned short As[2 * BM * BK];
    __shared__ unsigned short Bg[2 * BN * BK];
    __shared__ unsigned short Bu[2 * BN * BK];
    __shared__ int tok[BM];
    int tid = threadIdx.x;
    if (tid < BM) tok[tid] = disp[e * CBUF + m0 + tid];
    __syncthreads();

    int lane = tid & 63, w = tid >> 6;
    int cg = (lane & 3) ^ ((lane >> 3) & 3);   // swizzled source chunk
    int rl = lane >> 2;
    int rA0 = w * 32 + rl, rA1 = rA0 + 16;
    const unsigned short* srcA0 = xb + (size_t)tok[rA0] * DIM + cg * 8;
    const unsigned short* srcA1 = xb + (size_t)tok[rA1] * DIM + cg * 8;
    const unsigned short* srcG0 = gt + ((size_t)e * HID + n0 + rA0) * DIM + cg * 8;
    const unsigned short* srcG1 = gt + ((size_t)e * HID + n0 + rA1) * DIM + cg * 8;
    const unsigned short* srcU0 = ut + ((size_t)e * HID + n0 + rA0) * DIM + cg * 8;
    const unsigned short* srcU1 = ut + ((size_t)e * HID + n0 + rA1) * DIM + cg * 8;
    unsigned short* dA0 = As + (w * 32) * BK;
    unsigned short* dA1 = As + (w * 32 + 16) * BK;
    unsigned short* dG0 = Bg + (w * 32) * BK;
    unsigned short* dG1 = Bg + (w * 32 + 16) * BK;
    unsigned short* dU0 = Bu + (w * 32) * BK;
    unsigned short* dU1 = Bu + (w * 32 + 16) * BK;

    int wm = w >> 1, wn = w & 1;
    int quad = lane >> 4, ln = lane & 15;
    int swq = quad ^ ((ln >> 1) & 3);          // read-side swizzle

    f32x4 zero4 = {0.f, 0.f, 0.f, 0.f};
    f32x4 accg[4][4], accu[4][4];
    #pragma unroll
    for (int i = 0; i < 4; ++i)
        #pragma unroll
        for (int j = 0; j < 4; ++j) { accg[i][j] = zero4; accu[i][j] = zero4; }

    // prologue: stage tile 0 into buffer 0
    async16(srcA0, dA0); async16(srcA1, dA1);
    async16(srcG0, dG0); async16(srcG1, dG1);
    async16(srcU0, dU0); async16(srcU1, dU1);

    for (int k0 = 0; k0 < DIM; k0 += BK) {
        int cur = (k0 >> 5) & 1;
        asm volatile("s_waitcnt vmcnt(0)\n\ts_barrier" ::: "memory");
        if (k0 + BK < DIM) {
            int nx = cur ^ 1, nk = k0 + BK;
            async16(srcA0 + nk, dA0 + nx * (BM * BK));
            async16(srcA1 + nk, dA1 + nx * (BM * BK));
            async16(srcG0 + nk, dG0 + nx * (BN * BK));
            async16(srcG1 + nk, dG1 + nx * (BN * BK));
            async16(srcU0 + nk, dU0 + nx * (BN * BK));
            async16(srcU1 + nk, dU1 + nx * (BN * BK));
        }
        const unsigned short* Ab = As + cur * (BM * BK);
        const unsigned short* Gb = Bg + cur * (BN * BK);
        const unsigned short* Ub = Bu + cur * (BN * BK);
        short8 af[4], bgf[4], buf2[4];
        #pragma unroll
        for (int i = 0; i < 4; ++i)
            af[i] = *(const short8*)(Ab + (wm * 64 + i * 16 + ln) * BK + swq * 8);
        #pragma unroll
        for (int j = 0; j < 4; ++j) {
            bgf[j]  = *(const short8*)(Gb + (wn * 64 + j * 16 + ln) * BK + swq * 8);
            buf2[j] = *(const short8*)(Ub + (wn * 64 + j * 16 + ln) * BK + swq * 8);
        }
        #pragma unroll
        for (int i = 0; i < 4; ++i)
            #pragma unroll
            for (int j = 0; j < 4; ++j) {
                accg[i][j] = __builtin_amdgcn_mfma_f32_16x16x32_bf16(af[i], bgf[j],  accg[i][j], 0, 0, 0);
                accu[i][j] = __builtin_amdgcn_mfma_f32_16x16x32_bf16(af[i], buf2[j], accu[i][j], 0, 0, 0);
            }
    }
    #pragma unroll
    for (int i = 0; i < 4; ++i) {
        #pragma unroll
        for (int r = 0; r < 4; ++r) {
            int row = m0 + wm * 64 + i * 16 + quad * 4 + r;
            unsigned short* hrow = hidden + ((size_t)e * CBUF + row) * HID + n0 + wn * 64 + ln;
            #pragma unroll
            for (int j = 0; j < 4; ++j) {
                float g = accg[i][j][r];
                float u = accu[i][j][r];
                float sg = g / (1.f + __expf(-g));
                hrow[j * 16] = f2bf(sg * u);
            }
        }
    }
}

// ---------------- GEMM2: hidden @ down -> ebuf (bf16, per expert slot) ----------------
// 3-stage prefetch: DMA for tile k+2 issues before compute of tile k; steady
// state waits vmcnt(4) (one tile still in flight) - never a full drain.
__global__ __launch_bounds__(256, 2)
void gemm2_k(const unsigned short* __restrict__ hidden, const unsigned short* __restrict__ dt,
             const int* __restrict__ tmeta, unsigned short* __restrict__ ebuf) {
    int slot = blockIdx.y;
    if (slot >= tmeta[0]) return;
    int pk = tmeta[4 + slot];
    int e = pk >> 8, mt = pk & 255;
    int m0 = mt * BM, n0 = blockIdx.x * BN;

    __shared__ unsigned short As[3 * BM * BK];
    __shared__ unsigned short Bs[3 * BN * BK];
    int tid = threadIdx.x;

    int lane = tid & 63, w = tid >> 6;
    int cg = (lane & 3) ^ ((lane >> 3) & 3);
    int rl = lane >> 2;
    int rA0 = w * 32 + rl, rA1 = rA0 + 16;
    const unsigned short* srcA0 = hidden + ((size_t)e * CBUF + m0 + rA0) * HID + cg * 8;
    const unsigned short* srcA1 = hidden + ((size_t)e * CBUF + m0 + rA1) * HID + cg * 8;
    const unsigned short* srcB0 = dt + ((size_t)e * DIM + n0 + rA0) * HID + cg * 8;
    const unsigned short* srcB1 = dt + ((size_t)e * DIM + n0 + rA1) * HID + cg * 8;
    unsigned short* dA0 = As + (w * 32) * BK;
    unsigned short* dA1 = As + (w * 32 + 16) * BK;
    unsigned short* dB0 = Bs + (w * 32) * BK;
    unsigned short* dB1 = Bs + (w * 32 + 16) * BK;

    int wm = w >> 1, wn = w & 1;
    int quad = lane >> 4, ln = lane & 15;
    int swq = quad ^ ((ln >> 1) & 3);

    f32x4 zero4 = {0.f, 0.f, 0.f, 0.f};
    f32x4 acc[4][4];
    #pragma unroll
    for (int i = 0; i < 4; ++i)
        #pragma unroll
        for (int j = 0; j < 4; ++j) acc[i][j] = zero4;

    // prologue: tiles 0,1 into stages 0,1
    async16(srcA0, dA0); async16(srcA1, dA1);
    async16(srcB0, dB0); async16(srcB1, dB1);
    async16(srcA0 + BK, dA0 + BM * BK); async16(srcA1 + BK, dA1 + BM * BK);
    async16(srcB0 + BK, dB0 + BN * BK); async16(srcB1 + BK, dB1 + BN * BK);

    for (int k0 = 0; k0 < HID; k0 += BK) {
        int stage = (k0 >> 5) % 3;
        if (k0 + BK < HID) {
            asm volatile("s_waitcnt vmcnt(4)\n\ts_barrier" ::: "memory");
        } else {
            asm volatile("s_waitcnt vmcnt(0)\n\ts_barrier" ::: "memory");
        }
        if (k0 + 2 * BK < HID) {
            int nx = (stage + 2) % 3, nk = k0 + 2 * BK;   // stage buffer last read pre-barrier
            async16(srcA0 + nk, dA0 + nx * (BM * BK));
            async16(srcA1 + nk, dA1 + nx * (BM * BK));
            async16(srcB0 + nk, dB0 + nx * (BN * BK));
            async16(srcB1 + nk, dB1 + nx * (BN * BK));
        }
        const unsigned short* Ab = As + stage * (BM * BK);
        const unsigned short* Bb = Bs + stage * (BN * BK);
        short8 af[4], bf[4];
        #pragma unroll
        for (int i = 0; i < 4; ++i)
            af[i] = *(const short8*)(Ab + (wm * 64 + i * 16 + ln) * BK + swq * 8);
        #pragma unroll
        for (int j = 0; j < 4; ++j)
            bf[j] = *(const short8*)(Bb + (wn * 64 + j * 16 + ln) * BK + swq * 8);
        #pragma unroll
        for (int i = 0; i < 4; ++i)
            #pragma unroll
            for (int j = 0; j < 4; ++j)
                acc[i][j] = __builtin_amdgcn_mfma_f32_16x16x32_bf16(af[i], bf[j], acc[i][j], 0, 0, 0);
    }
    #pragma unroll
    for (int i = 0; i < 4; ++i) {
        #pragma unroll
        for (int r = 0; r < 4; ++r) {
            int row = m0 + wm * 64 + i * 16 + quad * 4 + r;
            unsigned short* erow = ebuf + ((size_t)e * CBUF + row) * DIM + n0 + wn * 64 + ln;
            #pragma unroll
            for (int j = 0; j < 4; ++j)
                erow[j * 16] = f2bf(acc[i][j][r]);
        }
    }
}

// ---------------- combine: out[t] = sum_k w[t,k] * ebuf[smap[t,k]] ----------------
__global__ __launch_bounds__(256)
void combine_k(const unsigned short* __restrict__ ebuf, const int* __restrict__ smap,
               const float* __restrict__ rwt, float* __restrict__ out) {
    int t = blockIdx.x * 2 + (threadIdx.x >> 7);
    int c = (threadIdx.x & 127) * 8;
    float acc[8];
    #pragma unroll
    for (int j = 0; j < 8; ++j) acc[j] = 0.f;
    #pragma unroll
    for (int k = 0; k < 2; ++k) {
        int sm = smap[t * 2 + k];
        if (sm >= 0) {
            float wgt = rwt[t * 2 + k];
            uint4 rv = *(const uint4*)(ebuf + (size_t)sm * DIM + c);
            unsigned int d[4] = {rv.x, rv.y, rv.z, rv.w};
            #pragma unroll
            for (int q = 0; q < 4; ++q) {
                acc[q * 2 + 0] += wgt * __uint_as_float(d[q] << 16);
                acc[q * 2 + 1] += wgt * __uint_as_float(d[q] & 0xffff0000u);
            }
        }
    }
    float4 o0 = {acc[0], acc[1], acc[2], acc[3]};
    float4 o1 = {acc[4], acc[5], acc[6], acc[7]};
    float* orow = out + (size_t)t * DIM + c;
    *(float4*)(orow + 0) = o0;
    *(float4*)(orow + 4) = o1;
}

extern "C" void kernel_launch(void* const* d_in, const int* in_sizes, int n_in,
                              void* d_out, int out_size, void* d_ws, size_t ws_size,
                              hipStream_t stream) {
    const float* x  = (const float*)d_in[0];   // (2,2048,1024)
    const float* rw = (const float*)d_in[1];   // (1024,16)
    const float* gw = (const float*)d_in[2];   // (16,1024,1024) [e][d][h]
    const float* uw = (const float*)d_in[3];   // (16,1024,1024) [e][d][h]
    const float* dw = (const float*)d_in[4];   // (16,1024,1024) [e][h][d]
    float* out = (float*)d_out;

    char* ws = (char*)d_ws;
    size_t off = 0;
    auto alloc = [&](size_t bytes) { void* p = ws + off; off += (bytes + 255) & ~(size_t)255; return p; };
    unsigned short* xb  = (unsigned short*)alloc((size_t)(T_TOK + 1) * DIM * 2);
    unsigned short* gt  = (unsigned short*)alloc((size_t)NE * DIM * HID * 2);  // [e][h][d]
    unsigned short* ut  = (unsigned short*)alloc((size_t)NE * DIM * HID * 2);  // [e][h][d]
    unsigned short* dtw = (unsigned short*)alloc((size_t)NE * DIM * HID * 2);  // [e][d][h]
    unsigned short* hid = (unsigned short*)alloc((size_t)NE * CBUF * HID * 2);
    int*   disp   = (int*)alloc((size_t)NE * CBUF * 4);
    int*   smap   = (int*)alloc((size_t)T_TOK * 2 * 4);
    int*   tmeta  = (int*)alloc((4 + MAXTILE) * 4);
    int*   re     = (int*)alloc((size_t)T_TOK * 2 * 4);
    float* rwt    = (float*)alloc((size_t)T_TOK * 2 * 4);
    // ebuf (40 MB) aliases gt+ut (64 MB): gate/up weights are dead after gemm1.
    unsigned short* ebuf = gt;
    (void)ws_size; (void)in_sizes; (void)n_in;

    convert_x_k<<<T_TOK + 1, 256, 0, stream>>>(x, xb);
    transpose_cvt_k<<<dim3(16, 16, 48), 256, 0, stream>>>(gw, uw, dw, gt, ut, dtw);
    router_k<<<T_TOK, 64, 0, stream>>>(x, rw, re, rwt);
    build_dispatch_k<<<1, 1024, 0, stream>>>(re, rwt, disp, smap, tmeta);
    gemm1_k<<<dim3(HID / BN, MAXTILE), 256, 0, stream>>>(xb, gt, ut, disp, tmeta, hid);
    gemm2_k<<<dim3(DIM / BN, MAXTILE), 256, 0, stream>>>(hid, dtw, tmeta, ebuf);
    combine_k<<<T_TOK / 2, 256, 0, stream>>>(ebuf, smap, rwt, out);
}

// Round 6
// 410.874 us; speedup vs baseline: 1.0102x; 1.0102x over previous
//
#include <hip/hip_runtime.h>
#include <math.h>

// Problem constants (B=2,S=2048 -> T=4096; D=H=1024; E=16; K=2; CF=1.25)
#define T_TOK 4096
#define DIM   1024
#define HID   1024
#define NE    16
#define CAP   640      // ceil(T*K/E*CF)
#define CBUF  1280     // K*CAP
#define BM 128
#define BN 64          // narrower n-tile: 16 n-tiles x ~70 m-tiles = ~1120 blocks (4.4/CU)
#define BK 64          // m97-style: 32 MFMA per wave per barrier pair
#define MAXTILE 160

typedef __attribute__((ext_vector_type(8))) short short8;   // 8 bf16 (4 VGPRs)
typedef __attribute__((ext_vector_type(4))) float f32x4;    // MFMA accumulator

static __device__ __forceinline__ unsigned short f2bf(float f) {
    unsigned int u = __float_as_uint(f);
    u += 0x7fff + ((u >> 16) & 1);   // RNE
    return (unsigned short)(u >> 16);
}

// async global->LDS DMA, 16B/lane; dst wave-uniform base, lane i -> dst+16*i.
// BK=64 rows are 128B = 8 chunks; chunk c of row r stored at c^(r&7) (source-
// side permute) so ds_read_b128 fragment reads are 2-way (free) without padding.
static __device__ __forceinline__ void async16(const void* g, void* l) {
    __builtin_amdgcn_global_load_lds((const __attribute__((address_space(1))) void*)g,
                                     (__attribute__((address_space(3))) void*)l, 16, 0, 0);
}

// ---------------- x -> bf16 (with zero padding row at index T) ----------------
__global__ void convert_x_k(const float* __restrict__ x, unsigned short* __restrict__ xb) {
    int i = blockIdx.x * blockDim.x + threadIdx.x;
    int base = i * 4;
    int row = base >> 10;
    ushort4 o;
    if (row < T_TOK) {
        float4 v = *(const float4*)(x + base);
        o.x = f2bf(v.x); o.y = f2bf(v.y); o.z = f2bf(v.z); o.w = f2bf(v.w);
    } else {
        o.x = 0; o.y = 0; o.z = 0; o.w = 0;
    }
    *(ushort4*)(xb + base) = o;
}

// ------------- fused weight transpose: fp32 [e][k][n] -> bf16 [e][n][k] -------------
// Temporal-locality restructure: each block owns 64 OUTPUT rows x full k=1024,
// looping 4 k-chunks of 256. Each output row's 2KB is produced back-to-back by
// one block (DRAM row stays hot); the 16 concurrent x-blocks read complementary
// 256B segments of the same input rows. LDS tile [n=64][k=256], stride 258.
#define TK 256
#define TST 258
__global__ __launch_bounds__(256)
void transpose_cvt_k(const float* __restrict__ W0, const float* __restrict__ W1,
                     const float* __restrict__ W2,
                     unsigned short* __restrict__ T0, unsigned short* __restrict__ T1,
                     unsigned short* __restrict__ T2) {
    __shared__ unsigned short s[64 * TST];   // 33 KB
    int zz = blockIdx.z;                 // 0..47
    int which = zz >> 4, e = zz & 15;
    const float* W = (which == 0) ? W0 : (which == 1) ? W1 : W2;
    unsigned short* T = (which == 0) ? T0 : (which == 1) ? T1 : T2;
    const float* Wp = W + (size_t)e * DIM * HID;
    unsigned short* Tp = T + (size_t)e * DIM * HID;
    int n0 = blockIdx.x * 64;
    int tid = threadIdx.x;
    int rsub = tid >> 2;          // 0..63
    int nofs = (tid & 3) * 16;    // 16-n segment within the 64-n slab

    for (int kc = 0; kc < 1024; kc += TK) {
        // phase 1: read TK k-rows x 64 n (256B-coalesced per 16-row group)
        #pragma unroll
        for (int p = 0; p < 4; ++p) {
            int kl = p * 64 + rsub;                     // local k (0..255)
            const float* rp = Wp + (size_t)(kc + kl) * 1024 + n0 + nofs;
            float4 v0 = *(const float4*)(rp + 0);
            float4 v1 = *(const float4*)(rp + 4);
            float4 v2 = *(const float4*)(rp + 8);
            float4 v3 = *(const float4*)(rp + 12);
            float vv[16] = {v0.x, v0.y, v0.z, v0.w, v1.x, v1.y, v1.z, v1.w,
                            v2.x, v2.y, v2.z, v2.w, v3.x, v3.y, v3.z, v3.w};
            #pragma unroll
            for (int v = 0; v < 16; ++v)
                s[(nofs + v) * TST + kl] = f2bf(vv[v]);
        }
        __syncthreads();
        // phase 2: write 64 n-rows x 512B (this chunk's k-range), k-contiguous
        {
            int n = tid >> 2;
            int qo = (tid & 3) * 64;                    // 64 k-elems = 128B per thread
            const unsigned short* srow = s + n * TST + qo;
            unsigned short* orow = Tp + (size_t)(n0 + n) * 1024 + kc + qo;
            #pragma unroll
            for (int jj = 0; jj < 8; ++jj) {
                uint4 o = *(const uint4*)(srow + jj * 8);
                *(uint4*)(orow + jj * 8) = o;
            }
        }
        __syncthreads();
    }
}

// ---------------- router: logits, softmax, top-2 (one wave per token) ----------------
__global__ void router_k(const float* __restrict__ x, const float* __restrict__ rw,
                         int* __restrict__ route_e, float* __restrict__ route_w) {
    int t = blockIdx.x;
    int lane = threadIdx.x;
    const float* xr = x + (size_t)t * DIM + lane * 16;
    float4 xv0 = *(const float4*)(xr + 0);
    float4 xv1 = *(const float4*)(xr + 4);
    float4 xv2 = *(const float4*)(xr + 8);
    float4 xv3 = *(const float4*)(xr + 12);
    float xl[16] = {xv0.x, xv0.y, xv0.z, xv0.w, xv1.x, xv1.y, xv1.z, xv1.w,
                    xv2.x, xv2.y, xv2.z, xv2.w, xv3.x, xv3.y, xv3.z, xv3.w};
    float p[16];
    #pragma unroll
    for (int e = 0; e < 16; ++e) p[e] = 0.f;
    #pragma unroll
    for (int j = 0; j < 16; ++j) {
        const float4* rp = (const float4*)(rw + (size_t)(lane * 16 + j) * 16);
        float4 r0 = rp[0], r1 = rp[1], r2 = rp[2], r3 = rp[3];
        float xv = xl[j];
        p[0]  += xv * r0.x; p[1]  += xv * r0.y; p[2]  += xv * r0.z; p[3]  += xv * r0.w;
        p[4]  += xv * r1.x; p[5]  += xv * r1.y; p[6]  += xv * r1.z; p[7]  += xv * r1.w;
        p[8]  += xv * r2.x; p[9]  += xv * r2.y; p[10] += xv * r2.z; p[11] += xv * r2.w;
        p[12] += xv * r3.x; p[13] += xv * r3.y; p[14] += xv * r3.z; p[15] += xv * r3.w;
    }
    #pragma unroll
    for (int off = 32; off > 0; off >>= 1) {
        #pragma unroll
        for (int e = 0; e < 16; ++e) p[e] += __shfl_xor(p[e], off);
    }
    if (lane == 0) {
        float m = p[0];
        #pragma unroll
        for (int e = 1; e < 16; ++e) m = fmaxf(m, p[e]);
        float s = 0.f;
        #pragma unroll
        for (int e = 0; e < 16; ++e) s = s + __expf(p[e] - m);
        float v0 = -1e30f, v1 = -1e30f; int i0 = 0, i1 = 0;
        #pragma unroll
        for (int e = 0; e < 16; ++e) {
            float v = p[e];
            if (v > v0)      { v1 = v0; i1 = i0; v0 = v; i0 = e; }
            else if (v > v1) { v1 = v;  i1 = e; }
        }
        route_e[t*2+0] = i0;  route_e[t*2+1] = i1;
        route_w[t*2+0] = __expf(v0 - m) / s;
        route_w[t*2+1] = __expf(v1 - m) / s;
    }
}

// ------- dispatch build: ballot rank/slot + inverse map smap + tile list -------
__global__ __launch_bounds__(1024)
void build_dispatch_k(const int* __restrict__ route_e, const float* __restrict__ route_w,
                      int* __restrict__ disp, int* __restrict__ smap, int* __restrict__ tmeta) {
    __shared__ unsigned char eidx[2 * T_TOK];
    __shared__ unsigned char keepf[2 * T_TOK];
    __shared__ int totals[NE];
    int tid = threadIdx.x;
    int wv = tid >> 6, lane = tid & 63;

    {   // route_e (8192 ints) -> bytes, coalesced
        int4 a = ((const int4*)route_e)[tid * 2];
        int4 b = ((const int4*)route_e)[tid * 2 + 1];
        unsigned int lo = (a.x & 0xff) | ((a.y & 0xff) << 8) | ((a.z & 0xff) << 16) | ((a.w & 0xff) << 24);
        unsigned int hi = (b.x & 0xff) | ((b.y & 0xff) << 8) | ((b.z & 0xff) << 16) | ((b.w & 0xff) << 24);
        uint2 pk; pk.x = lo; pk.y = hi;
        *(uint2*)(eidx + tid * 8) = pk;
    }
    for (int i = tid; i < 2 * T_TOK; i += 1024) smap[i] = -1;
    __syncthreads();

    unsigned long long below = (lane == 0) ? 0ull : ((~0ull) >> (64 - lane));
    #pragma unroll
    for (int s = 0; s < 2; ++s) {      // keep = token-order rank in (e,k) stream < CAP
        int st = wv + s * 16;
        int e = st >> 1, k = st & 1;
        int run = 0;
        for (int base = 0; base < T_TOK; base += 64) {
            int t = base + lane;
            int hit = (eidx[t * 2 + k] == e);
            unsigned long long m = __ballot(hit);
            int rank = run + __popcll(m & below);
            if (hit) keepf[t * 2 + k] = (rank < CAP) ? 1 : 0;
            run += __popcll(m);
        }
    }
    __syncthreads();

    {   // slot = flat-order rank among kept entries of expert e (one wave per expert)
        int e = wv;
        int run = 0;
        for (int base = 0; base < 2 * T_TOK; base += 64) {
            int f = base + lane;
            int hit = (eidx[f] == e) && keepf[f];
            unsigned long long m = __ballot(hit);
            int slot = run + __popcll(m & below);
            if (hit) {
                disp[e * CBUF + slot] = f >> 1;
                smap[f] = e * CBUF + slot;
            }
            run += __popcll(m);
        }
        if (lane == 0) totals[e] = run;
    }
    __syncthreads();

    for (int i = tid; i < NE * CBUF; i += 1024) {   // pad unused slots -> zero row
        int e = i / CBUF, s = i - e * CBUF;
        if (s >= totals[e]) disp[i] = T_TOK;
    }

    if (tid == 0) {   // active-tile list
        int n = 0;
        for (int e = 0; e < NE; ++e) {
            int ntl = (totals[e] + BM - 1) / BM;
            for (int m = 0; m < ntl; ++m) { tmeta[4 + n] = (e << 8) | m; ++n; }
        }
        tmeta[0] = n;
    }
}

// ---------------- GEMM1: xe @ {gate,up} fused + SiLU -> hidden (bf16) ----------------
// m97 structure: BK=64, single-buffer LDS (33 KB), 2 barriers/iter, 4 blocks/CU.
__global__ __launch_bounds__(256, 2)
void gemm1_k(const unsigned short* __restrict__ xb, const unsigned short* __restrict__ gt,
             const unsigned short* __restrict__ ut, const int* __restrict__ disp,
             const int* __restrict__ tmeta, unsigned short* __restrict__ hidden) {
    int slot = blockIdx.y;
    if (slot >= tmeta[0]) return;
    int pk = tmeta[4 + slot];
    int e = pk >> 8, mt = pk & 255;
    int m0 = mt * BM, n0 = blockIdx.x * BN;

    __shared__ unsigned short As[BM * BK];   // 16 KB
    __shared__ unsigned short Bg[BN * BK];   // 8 KB
    __shared__ unsigned short Bu[BN * BK];   // 8 KB
    __shared__ int tok[BM];
    int tid = threadIdx.x;
    if (tid < BM) tok[tid] = disp[e * CBUF + m0 + tid];
    __syncthreads();

    int lane = tid & 63, w = tid >> 6;
    int r8 = lane >> 3, c8 = lane & 7;
    int csw = (c8 ^ r8) * 8;                  // swizzled source k-offset (elems)

    // A: 4 DMA issues/thread (8 rows each); B: 2 issues/thread per tensor
    const unsigned short* asrc[4];
    #pragma unroll
    for (int q = 0; q < 4; ++q)
        asrc[q] = xb + (size_t)tok[w * 32 + q * 8 + r8] * DIM + csw;
    const unsigned short* gsrc[2];
    const unsigned short* usrc[2];
    #pragma unroll
    for (int q = 0; q < 2; ++q) {
        int row = n0 + w * 16 + q * 8 + r8;
        gsrc[q] = gt + ((size_t)e * HID + row) * DIM + csw;
        usrc[q] = ut + ((size_t)e * HID + row) * DIM + csw;
    }

    int wm = w >> 1, wn = w & 1;
    int quad = lane >> 4, ln = lane & 15;
    int l7 = ln & 7;

    f32x4 zero4 = {0.f, 0.f, 0.f, 0.f};
    f32x4 accg[4][2], accu[4][2];
    #pragma unroll
    for (int i = 0; i < 4; ++i)
        #pragma unroll
        for (int j = 0; j < 2; ++j) { accg[i][j] = zero4; accu[i][j] = zero4; }

    for (int k0 = 0; k0 < DIM; k0 += BK) {
        #pragma unroll
        for (int q = 0; q < 4; ++q)
            async16(asrc[q] + k0, As + (w * 32 + q * 8) * BK);
        #pragma unroll
        for (int q = 0; q < 2; ++q) {
            async16(gsrc[q] + k0, Bg + (w * 16 + q * 8) * BK);
            async16(usrc[q] + k0, Bu + (w * 16 + q * 8) * BK);
        }
        __syncthreads();   // compiler emits vmcnt(0) drain here - DMA complete
        #pragma unroll
        for (int kh = 0; kh < 2; ++kh) {
            int ck = ((quad + 4 * kh) ^ l7) * 8;
            short8 af[4], bgf[2], buf2[2];
            #pragma unroll
            for (int i = 0; i < 4; ++i)
                af[i] = *(const short8*)(As + (wm * 64 + i * 16 + ln) * BK + ck);
            #pragma unroll
            for (int j = 0; j < 2; ++j) {
                bgf[j]  = *(const short8*)(Bg + (wn * 32 + j * 16 + ln) * BK + ck);
                buf2[j] = *(const short8*)(Bu + (wn * 32 + j * 16 + ln) * BK + ck);
            }
            #pragma unroll
            for (int i = 0; i < 4; ++i)
                #pragma unroll
                for (int j = 0; j < 2; ++j) {
                    accg[i][j] = __builtin_amdgcn_mfma_f32_16x16x32_bf16(af[i], bgf[j],  accg[i][j], 0, 0, 0);
                    accu[i][j] = __builtin_amdgcn_mfma_f32_16x16x32_bf16(af[i], buf2[j], accu[i][j], 0, 0, 0);
                }
        }
        __syncthreads();   // protect LDS until all waves finished reading
    }
    #pragma unroll
    for (int i = 0; i < 4; ++i) {
        #pragma unroll
        for (int r = 0; r < 4; ++r) {
            int row = m0 + wm * 64 + i * 16 + quad * 4 + r;
            unsigned short* hrow = hidden + ((size_t)e * CBUF + row) * HID + n0 + wn * 32 + ln;
            #pragma unroll
            for (int j = 0; j < 2; ++j) {
                float g = accg[i][j][r];
                float u = accu[i][j][r];
                float sg = g / (1.f + __expf(-g));
                hrow[j * 16] = f2bf(sg * u);
            }
        }
    }
}

// ---------------- GEMM2: hidden @ down -> ebuf (bf16, per expert slot) ----------------
__global__ __launch_bounds__(256, 2)
void gemm2_k(const unsigned short* __restrict__ hidden, const unsigned short* __restrict__ dt,
             const int* __restrict__ tmeta, unsigned short* __restrict__ ebuf) {
    int slot = blockIdx.y;
    if (slot >= tmeta[0]) return;
    int pk = tmeta[4 + slot];
    int e = pk >> 8, mt = pk & 255;
    int m0 = mt * BM, n0 = blockIdx.x * BN;

    __shared__ unsigned short As[BM * BK];   // 16 KB
    __shared__ unsigned short Bs[BN * BK];   // 8 KB
    int tid = threadIdx.x;

    int lane = tid & 63, w = tid >> 6;
    int r8 = lane >> 3, c8 = lane & 7;
    int csw = (c8 ^ r8) * 8;

    const unsigned short* asrc[4];
    #pragma unroll
    for (int q = 0; q < 4; ++q)
        asrc[q] = hidden + ((size_t)e * CBUF + m0 + w * 32 + q * 8 + r8) * HID + csw;
    const unsigned short* bsrc[2];
    #pragma unroll
    for (int q = 0; q < 2; ++q)
        bsrc[q] = dt + ((size_t)e * DIM + n0 + w * 16 + q * 8 + r8) * HID + csw;

    int wm = w >> 1, wn = w & 1;
    int quad = lane >> 4, ln = lane & 15;
    int l7 = ln & 7;

    f32x4 zero4 = {0.f, 0.f, 0.f, 0.f};
    f32x4 acc[4][2];
    #pragma unroll
    for (int i = 0; i < 4; ++i)
        #pragma unroll
        for (int j = 0; j < 2; ++j) acc[i][j] = zero4;

    for (int k0 = 0; k0 < HID; k0 += BK) {
        #pragma unroll
        for (int q = 0; q < 4; ++q)
            async16(asrc[q] + k0, As + (w * 32 + q * 8) * BK);
        #pragma unroll
        for (int q = 0; q < 2; ++q)
            async16(bsrc[q] + k0, Bs + (w * 16 + q * 8) * BK);
        __syncthreads();
        #pragma unroll
        for (int kh = 0; kh < 2; ++kh) {
            int ck = ((quad + 4 * kh) ^ l7) * 8;
            short8 af[4], bf[2];
            #pragma unroll
            for (int i = 0; i < 4; ++i)
                af[i] = *(const short8*)(As + (wm * 64 + i * 16 + ln) * BK + ck);
            #pragma unroll
            for (int j = 0; j < 2; ++j)
                bf[j] = *(const short8*)(Bs + (wn * 32 + j * 16 + ln) * BK + ck);
            #pragma unroll
            for (int i = 0; i < 4; ++i)
                #pragma unroll
                for (int j = 0; j < 2; ++j)
                    acc[i][j] = __builtin_amdgcn_mfma_f32_16x16x32_bf16(af[i], bf[j], acc[i][j], 0, 0, 0);
        }
        __syncthreads();
    }
    #pragma unroll
    for (int i = 0; i < 4; ++i) {
        #pragma unroll
        for (int r = 0; r < 4; ++r) {
            int row = m0 + wm * 64 + i * 16 + quad * 4 + r;
            unsigned short* erow = ebuf + ((size_t)e * CBUF + row) * DIM + n0 + wn * 32 + ln;
            #pragma unroll
            for (int j = 0; j < 2; ++j)
                erow[j * 16] = f2bf(acc[i][j][r]);
        }
    }
}

// ---------------- combine: out[t] = sum_k w[t,k] * ebuf[smap[t,k]] ----------------
__global__ __launch_bounds__(256)
void combine_k(const unsigned short* __restrict__ ebuf, const int* __restrict__ smap,
               const float* __restrict__ rwt, float* __restrict__ out) {
    int t = blockIdx.x * 2 + (threadIdx.x >> 7);
    int c = (threadIdx.x & 127) * 8;
    float acc[8];
    #pragma unroll
    for (int j = 0; j < 8; ++j) acc[j] = 0.f;
    #pragma unroll
    for (int k = 0; k < 2; ++k) {
        int sm = smap[t * 2 + k];
        if (sm >= 0) {
            float wgt = rwt[t * 2 + k];
            uint4 rv = *(const uint4*)(ebuf + (size_t)sm * DIM + c);
            unsigned int d[4] = {rv.x, rv.y, rv.z, rv.w};
            #pragma unroll
            for (int q = 0; q < 4; ++q) {
                acc[q * 2 + 0] += wgt * __uint_as_float(d[q] << 16);
                acc[q * 2 + 1] += wgt * __uint_as_float(d[q] & 0xffff0000u);
            }
        }
    }
    float4 o0 = {acc[0], acc[1], acc[2], acc[3]};
    float4 o1 = {acc[4], acc[5], acc[6], acc[7]};
    float* orow = out + (size_t)t * DIM + c;
    *(float4*)(orow + 0) = o0;
    *(float4*)(orow + 4) = o1;
}

extern "C" void kernel_launch(void* const* d_in, const int* in_sizes, int n_in,
                              void* d_out, int out_size, void* d_ws, size_t ws_size,
                              hipStream_t stream) {
    const float* x  = (const float*)d_in[0];   // (2,2048,1024)
    const float* rw = (const float*)d_in[1];   // (1024,16)
    const float* gw = (const float*)d_in[2];   // (16,1024,1024) [e][d][h]
    const float* uw = (const float*)d_in[3];   // (16,1024,1024) [e][d][h]
    const float* dw = (const float*)d_in[4];   // (16,1024,1024) [e][h][d]
    float* out = (float*)d_out;

    char* ws = (char*)d_ws;
    size_t off = 0;
    auto alloc = [&](size_t bytes) { void* p = ws + off; off += (bytes + 255) & ~(size_t)255; return p; };
    unsigned short* xb  = (unsigned short*)alloc((size_t)(T_TOK + 1) * DIM * 2);
    unsigned short* gt  = (unsigned short*)alloc((size_t)NE * DIM * HID * 2);  // [e][h][d]
    unsigned short* ut  = (unsigned short*)alloc((size_t)NE * DIM * HID * 2);  // [e][h][d]
    unsigned short* dtw = (unsigned short*)alloc((size_t)NE * DIM * HID * 2);  // [e][d][h]
    unsigned short* hid = (unsigned short*)alloc((size_t)NE * CBUF * HID * 2);
    int*   disp   = (int*)alloc((size_t)NE * CBUF * 4);
    int*   smap   = (int*)alloc((size_t)T_TOK * 2 * 4);
    int*   tmeta  = (int*)alloc((4 + MAXTILE) * 4);
    int*   re     = (int*)alloc((size_t)T_TOK * 2 * 4);
    float* rwt    = (float*)alloc((size_t)T_TOK * 2 * 4);
    // ebuf (40 MB) aliases gt+ut (64 MB): gate/up weights are dead after gemm1.
    unsigned short* ebuf = gt;
    (void)ws_size; (void)in_sizes; (void)n_in;

    convert_x_k<<<T_TOK + 1, 256, 0, stream>>>(x, xb);
    transpose_cvt_k<<<dim3(16, 1, 48), 256, 0, stream>>>(gw, uw, dw, gt, ut, dtw);
    router_k<<<T_TOK, 64, 0, stream>>>(x, rw, re, rwt);
    build_dispatch_k<<<1, 1024, 0, stream>>>(re, rwt, disp, smap, tmeta);
    gemm1_k<<<dim3(HID / BN, MAXTILE), 256, 0, stream>>>(xb, gt, ut, disp, tmeta, hid);
    gemm2_k<<<dim3(DIM / BN, MAXTILE), 256, 0, stream>>>(hid, dtw, tmeta, ebuf);
    combine_k<<<T_TOK / 2, 256, 0, stream>>>(ebuf, smap, rwt, out);
}

// Round 7
// 407.668 us; speedup vs baseline: 1.0182x; 1.0079x over previous
//
#include <hip/hip_runtime.h>
#include <math.h>

// Problem constants (B=2,S=2048 -> T=4096; D=H=1024; E=16; K=2; CF=1.25)
#define T_TOK 4096
#define DIM   1024
#define HID   1024
#define NE    16
#define CAP   640      // ceil(T*K/E*CF)
#define CBUF  1280     // K*CAP
#define BM 128
#define BN 64          // 16 n-tiles x ~70 active m-tiles = ~1120 blocks (4.4/CU)
#define BK 32
#define MAXTILE 160

typedef __attribute__((ext_vector_type(8))) short short8;   // 8 bf16 (4 VGPRs)
typedef __attribute__((ext_vector_type(4))) float f32x4;    // MFMA accumulator

static __device__ __forceinline__ unsigned short f2bf(float f) {
    unsigned int u = __float_as_uint(f);
    u += 0x7fff + ((u >> 16) & 1);   // RNE
    return (unsigned short)(u >> 16);
}

// async global->LDS DMA, 16B/lane; dst wave-uniform base, lane i -> dst+16*i.
// Rows are 64B = 4 chunks; chunk c of row r stored at c^((r>>1)&3) (source-side
// permute) so ds_read_b128 fragment reads are 2-way (free) without padding.
// Verified conflicts=0 in R3 profile.
static __device__ __forceinline__ void async16(const void* g, void* l) {
    __builtin_amdgcn_global_load_lds((const __attribute__((address_space(1))) void*)g,
                                     (__attribute__((address_space(3))) void*)l, 16, 0, 0);
}

// ---------------- x -> bf16 (with zero padding row at index T) ----------------
__global__ void convert_x_k(const float* __restrict__ x, unsigned short* __restrict__ xb) {
    int i = blockIdx.x * blockDim.x + threadIdx.x;
    int base = i * 4;
    int row = base >> 10;
    ushort4 o;
    if (row < T_TOK) {
        float4 v = *(const float4*)(x + base);
        o.x = f2bf(v.x); o.y = f2bf(v.y); o.z = f2bf(v.z); o.w = f2bf(v.w);
    } else {
        o.x = 0; o.y = 0; o.z = 0; o.w = 0;
    }
    *(ushort4*)(xb + base) = o;
}

// ------------- fused weight transpose: fp32 [e][k][n] -> bf16 [e][n][k] -------------
// R5 form (best measured: ~85 us). Interior variants (write coalescing, bank
// conflicts, temporal locality) all measured 85-105 us at ~2.0-2.4 TB/s: the
// cap is structural to the read-transpose-write stream; don't re-tune interior.
#define TSP 66
__global__ void transpose_cvt_k(const float* __restrict__ W0, const float* __restrict__ W1,
                                const float* __restrict__ W2,
                                unsigned short* __restrict__ T0, unsigned short* __restrict__ T1,
                                unsigned short* __restrict__ T2) {
    __shared__ unsigned short s[64 * TSP];
    int zz = blockIdx.z;                 // 0..47
    int which = zz >> 4, e = zz & 15;
    const float* W = (which == 0) ? W0 : (which == 1) ? W1 : W2;
    unsigned short* T = (which == 0) ? T0 : (which == 1) ? T1 : T2;
    const float* Wp = W + (size_t)e * DIM * HID;
    unsigned short* Tp = T + (size_t)e * DIM * HID;
    int k0 = blockIdx.y * 64, n0 = blockIdx.x * 64;
    int tid = threadIdx.x;
    int tx = tid & 15, ty = tid >> 4;
    #pragma unroll
    for (int i = 0; i < 4; ++i) {
        int k = ty + i * 16;
        float4 v = *(const float4*)(Wp + (size_t)(k0 + k) * 1024 + n0 + tx * 4);
        int nb = tx * 4;
        s[(nb + 0) * TSP + k] = f2bf(v.x);
        s[(nb + 1) * TSP + k] = f2bf(v.y);
        s[(nb + 2) * TSP + k] = f2bf(v.z);
        s[(nb + 3) * TSP + k] = f2bf(v.w);
    }
    __syncthreads();
    int j = tid & 7, kseg = j * 8;        // 16B segment of the output row
    int nb2 = tid >> 3;                   // 0..31
    #pragma unroll
    for (int h = 0; h < 2; ++h) {
        int n = h * 32 + nb2;
        uint4 o;
        o.x = *(const unsigned int*)&s[n * TSP + kseg + 0];
        o.y = *(const unsigned int*)&s[n * TSP + kseg + 2];
        o.z = *(const unsigned int*)&s[n * TSP + kseg + 4];
        o.w = *(const unsigned int*)&s[n * TSP + kseg + 6];
        *(uint4*)(Tp + (size_t)(n0 + n) * 1024 + k0 + kseg) = o;
    }
}

// ---------------- router: logits, softmax, top-2 (one wave per token) ----------------
__global__ void router_k(const float* __restrict__ x, const float* __restrict__ rw,
                         int* __restrict__ route_e, float* __restrict__ route_w) {
    int t = blockIdx.x;
    int lane = threadIdx.x;
    const float* xr = x + (size_t)t * DIM + lane * 16;
    float4 xv0 = *(const float4*)(xr + 0);
    float4 xv1 = *(const float4*)(xr + 4);
    float4 xv2 = *(const float4*)(xr + 8);
    float4 xv3 = *(const float4*)(xr + 12);
    float xl[16] = {xv0.x, xv0.y, xv0.z, xv0.w, xv1.x, xv1.y, xv1.z, xv1.w,
                    xv2.x, xv2.y, xv2.z, xv2.w, xv3.x, xv3.y, xv3.z, xv3.w};
    float p[16];
    #pragma unroll
    for (int e = 0; e < 16; ++e) p[e] = 0.f;
    #pragma unroll
    for (int j = 0; j < 16; ++j) {
        const float4* rp = (const float4*)(rw + (size_t)(lane * 16 + j) * 16);
        float4 r0 = rp[0], r1 = rp[1], r2 = rp[2], r3 = rp[3];
        float xv = xl[j];
        p[0]  += xv * r0.x; p[1]  += xv * r0.y; p[2]  += xv * r0.z; p[3]  += xv * r0.w;
        p[4]  += xv * r1.x; p[5]  += xv * r1.y; p[6]  += xv * r1.z; p[7]  += xv * r1.w;
        p[8]  += xv * r2.x; p[9]  += xv * r2.y; p[10] += xv * r2.z; p[11] += xv * r2.w;
        p[12] += xv * r3.x; p[13] += xv * r3.y; p[14] += xv * r3.z; p[15] += xv * r3.w;
    }
    #pragma unroll
    for (int off = 32; off > 0; off >>= 1) {
        #pragma unroll
        for (int e = 0; e < 16; ++e) p[e] += __shfl_xor(p[e], off);
    }
    if (lane == 0) {
        float m = p[0];
        #pragma unroll
        for (int e = 1; e < 16; ++e) m = fmaxf(m, p[e]);
        float s = 0.f;
        #pragma unroll
        for (int e = 0; e < 16; ++e) s = s + __expf(p[e] - m);
        float v0 = -1e30f, v1 = -1e30f; int i0 = 0, i1 = 0;
        #pragma unroll
        for (int e = 0; e < 16; ++e) {
            float v = p[e];
            if (v > v0)      { v1 = v0; i1 = i0; v0 = v; i0 = e; }
            else if (v > v1) { v1 = v;  i1 = e; }
        }
        route_e[t*2+0] = i0;  route_e[t*2+1] = i1;
        route_w[t*2+0] = __expf(v0 - m) / s;
        route_w[t*2+1] = __expf(v1 - m) / s;
    }
}

// ------- dispatch build: ballot rank/slot + inverse map smap + tile list -------
__global__ __launch_bounds__(1024)
void build_dispatch_k(const int* __restrict__ route_e, const float* __restrict__ route_w,
                      int* __restrict__ disp, int* __restrict__ smap, int* __restrict__ tmeta) {
    __shared__ unsigned char eidx[2 * T_TOK];
    __shared__ unsigned char keepf[2 * T_TOK];
    __shared__ int totals[NE];
    int tid = threadIdx.x;
    int wv = tid >> 6, lane = tid & 63;

    {   // route_e (8192 ints) -> bytes, coalesced
        int4 a = ((const int4*)route_e)[tid * 2];
        int4 b = ((const int4*)route_e)[tid * 2 + 1];
        unsigned int lo = (a.x & 0xff) | ((a.y & 0xff) << 8) | ((a.z & 0xff) << 16) | ((a.w & 0xff) << 24);
        unsigned int hi = (b.x & 0xff) | ((b.y & 0xff) << 8) | ((b.z & 0xff) << 16) | ((b.w & 0xff) << 24);
        uint2 pk; pk.x = lo; pk.y = hi;
        *(uint2*)(eidx + tid * 8) = pk;
    }
    for (int i = tid; i < 2 * T_TOK; i += 1024) smap[i] = -1;
    __syncthreads();

    unsigned long long below = (lane == 0) ? 0ull : ((~0ull) >> (64 - lane));
    #pragma unroll
    for (int s = 0; s < 2; ++s) {      // keep = token-order rank in (e,k) stream < CAP
        int st = wv + s * 16;
        int e = st >> 1, k = st & 1;
        int run = 0;
        for (int base = 0; base < T_TOK; base += 64) {
            int t = base + lane;
            int hit = (eidx[t * 2 + k] == e);
            unsigned long long m = __ballot(hit);
            int rank = run + __popcll(m & below);
            if (hit) keepf[t * 2 + k] = (rank < CAP) ? 1 : 0;
            run += __popcll(m);
        }
    }
    __syncthreads();

    {   // slot = flat-order rank among kept entries of expert e (one wave per expert)
        int e = wv;
        int run = 0;
        for (int base = 0; base < 2 * T_TOK; base += 64) {
            int f = base + lane;
            int hit = (eidx[f] == e) && keepf[f];
            unsigned long long m = __ballot(hit);
            int slot = run + __popcll(m & below);
            if (hit) {
                disp[e * CBUF + slot] = f >> 1;
                smap[f] = e * CBUF + slot;
            }
            run += __popcll(m);
        }
        if (lane == 0) totals[e] = run;
    }
    __syncthreads();

    for (int i = tid; i < NE * CBUF; i += 1024) {   // pad unused slots -> zero row
        int e = i / CBUF, s = i - e * CBUF;
        if (s >= totals[e]) disp[i] = T_TOK;
    }

    if (tid == 0) {   // active-tile list
        int n = 0;
        for (int e = 0; e < NE; ++e) {
            int ntl = (totals[e] + BM - 1) / BM;
            for (int m = 0; m < ntl; ++m) { tmeta[4 + n] = (e << 8) | m; ++n; }
        }
        tmeta[0] = n;
    }
}

// ---------------- GEMM1: xe @ {gate,up} fused + SiLU -> hidden (bf16) ----------------
// BM=128/BN=64/BK=32, double-buffered DMA pipeline with raw s_barrier (no
// compiler vmcnt(0)-before-compute drain): tile k+1's DMA in flight through
// compute of tile k. LDS 33 KB -> 4 blocks/CU; 1120-block grid.
__global__ __launch_bounds__(256, 2)
void gemm1_k(const unsigned short* __restrict__ xb, const unsigned short* __restrict__ gt,
             const unsigned short* __restrict__ ut, const int* __restrict__ disp,
             const int* __restrict__ tmeta, unsigned short* __restrict__ hidden) {
    int slot = blockIdx.y;
    if (slot >= tmeta[0]) return;
    int pk = tmeta[4 + slot];
    int e = pk >> 8, mt = pk & 255;
    int m0 = mt * BM, n0 = blockIdx.x * BN;

    __shared__ unsigned short As[2 * BM * BK];   // 16 KB
    __shared__ unsigned short Bg[2 * BN * BK];   // 8 KB
    __shared__ unsigned short Bu[2 * BN * BK];   // 8 KB
    __shared__ int tok[BM];
    int tid = threadIdx.x;
    if (tid < BM) tok[tid] = disp[e * CBUF + m0 + tid];
    __syncthreads();

    int lane = tid & 63, w = tid >> 6;
    int cg = (lane & 3) ^ ((lane >> 3) & 3);   // swizzled source chunk
    int rl = lane >> 2;                         // local row in 16-row group
    int rA0 = w * 32 + rl, rA1 = rA0 + 16;
    const unsigned short* srcA0 = xb + (size_t)tok[rA0] * DIM + cg * 8;
    const unsigned short* srcA1 = xb + (size_t)tok[rA1] * DIM + cg * 8;
    const unsigned short* srcG  = gt + ((size_t)e * HID + n0 + w * 16 + rl) * DIM + cg * 8;
    const unsigned short* srcU  = ut + ((size_t)e * HID + n0 + w * 16 + rl) * DIM + cg * 8;
    unsigned short* dA0 = As + (w * 32) * BK;
    unsigned short* dA1 = As + (w * 32 + 16) * BK;
    unsigned short* dG  = Bg + (w * 16) * BK;
    unsigned short* dU  = Bu + (w * 16) * BK;

    int wm = w >> 1, wn = w & 1;
    int quad = lane >> 4, ln = lane & 15;
    int swq = quad ^ ((ln >> 1) & 3);          // read-side swizzle

    f32x4 zero4 = {0.f, 0.f, 0.f, 0.f};
    f32x4 accg[4][2], accu[4][2];
    #pragma unroll
    for (int i = 0; i < 4; ++i)
        #pragma unroll
        for (int j = 0; j < 2; ++j) { accg[i][j] = zero4; accu[i][j] = zero4; }

    // prologue: tile 0 -> buffer 0
    async16(srcA0, dA0); async16(srcA1, dA1);
    async16(srcG, dG);   async16(srcU, dU);

    for (int k0 = 0; k0 < DIM; k0 += BK) {
        int cur = (k0 >> 5) & 1;
        // own-DMA wait + barrier: tile k fully visible; buffer cur^1 free
        // (all waves finished reading it before the previous barrier).
        asm volatile("s_waitcnt vmcnt(0)\n\ts_barrier" ::: "memory");
        if (k0 + BK < DIM) {
            int nx = cur ^ 1, nk = k0 + BK;
            async16(srcA0 + nk, dA0 + nx * (BM * BK));
            async16(srcA1 + nk, dA1 + nx * (BM * BK));
            async16(srcG + nk,  dG + nx * (BN * BK));
            async16(srcU + nk,  dU + nx * (BN * BK));
        }
        const unsigned short* Ab = As + cur * (BM * BK);
        const unsigned short* Gb = Bg + cur * (BN * BK);
        const unsigned short* Ub = Bu + cur * (BN * BK);
        short8 af[4], bgf[2], buf2[2];
        #pragma unroll
        for (int i = 0; i < 4; ++i)
            af[i] = *(const short8*)(Ab + (wm * 64 + i * 16 + ln) * BK + swq * 8);
        #pragma unroll
        for (int j = 0; j < 2; ++j) {
            bgf[j]  = *(const short8*)(Gb + (wn * 32 + j * 16 + ln) * BK + swq * 8);
            buf2[j] = *(const short8*)(Ub + (wn * 32 + j * 16 + ln) * BK + swq * 8);
        }
        #pragma unroll
        for (int i = 0; i < 4; ++i)
            #pragma unroll
            for (int j = 0; j < 2; ++j) {
                accg[i][j] = __builtin_amdgcn_mfma_f32_16x16x32_bf16(af[i], bgf[j],  accg[i][j], 0, 0, 0);
                accu[i][j] = __builtin_amdgcn_mfma_f32_16x16x32_bf16(af[i], buf2[j], accu[i][j], 0, 0, 0);
            }
    }
    #pragma unroll
    for (int i = 0; i < 4; ++i) {
        #pragma unroll
        for (int r = 0; r < 4; ++r) {
            int row = m0 + wm * 64 + i * 16 + quad * 4 + r;
            unsigned short* hrow = hidden + ((size_t)e * CBUF + row) * HID + n0 + wn * 32 + ln;
            #pragma unroll
            for (int j = 0; j < 2; ++j) {
                float g = accg[i][j][r];
                float u = accu[i][j][r];
                float sg = g / (1.f + __expf(-g));
                hrow[j * 16] = f2bf(sg * u);
            }
        }
    }
}

// ---------------- GEMM2: hidden @ down -> ebuf (bf16, per expert slot) ----------------
// Same dbuf pipeline; LDS 24 KB -> 6 blocks/CU.
__global__ __launch_bounds__(256, 2)
void gemm2_k(const unsigned short* __restrict__ hidden, const unsigned short* __restrict__ dt,
             const int* __restrict__ tmeta, unsigned short* __restrict__ ebuf) {
    int slot = blockIdx.y;
    if (slot >= tmeta[0]) return;
    int pk = tmeta[4 + slot];
    int e = pk >> 8, mt = pk & 255;
    int m0 = mt * BM, n0 = blockIdx.x * BN;

    __shared__ unsigned short As[2 * BM * BK];   // 16 KB
    __shared__ unsigned short Bs[2 * BN * BK];   // 8 KB
    int tid = threadIdx.x;

    int lane = tid & 63, w = tid >> 6;
    int cg = (lane & 3) ^ ((lane >> 3) & 3);
    int rl = lane >> 2;
    int rA0 = w * 32 + rl, rA1 = rA0 + 16;
    const unsigned short* srcA0 = hidden + ((size_t)e * CBUF + m0 + rA0) * HID + cg * 8;
    const unsigned short* srcA1 = hidden + ((size_t)e * CBUF + m0 + rA1) * HID + cg * 8;
    const unsigned short* srcB  = dt + ((size_t)e * DIM + n0 + w * 16 + rl) * HID + cg * 8;
    unsigned short* dA0 = As + (w * 32) * BK;
    unsigned short* dA1 = As + (w * 32 + 16) * BK;
    unsigned short* dB  = Bs + (w * 16) * BK;

    int wm = w >> 1, wn = w & 1;
    int quad = lane >> 4, ln = lane & 15;
    int swq = quad ^ ((ln >> 1) & 3);

    f32x4 zero4 = {0.f, 0.f, 0.f, 0.f};
    f32x4 acc[4][2];
    #pragma unroll
    for (int i = 0; i < 4; ++i)
        #pragma unroll
        for (int j = 0; j < 2; ++j) acc[i][j] = zero4;

    async16(srcA0, dA0); async16(srcA1, dA1);
    async16(srcB, dB);

    for (int k0 = 0; k0 < HID; k0 += BK) {
        int cur = (k0 >> 5) & 1;
        asm volatile("s_waitcnt vmcnt(0)\n\ts_barrier" ::: "memory");
        if (k0 + BK < HID) {
            int nx = cur ^ 1, nk = k0 + BK;
            async16(srcA0 + nk, dA0 + nx * (BM * BK));
            async16(srcA1 + nk, dA1 + nx * (BM * BK));
            async16(srcB + nk,  dB + nx * (BN * BK));
        }
        const unsigned short* Ab = As + cur * (BM * BK);
        const unsigned short* Bb = Bs + cur * (BN * BK);
        short8 af[4], bf[2];
        #pragma unroll
        for (int i = 0; i < 4; ++i)
            af[i] = *(const short8*)(Ab + (wm * 64 + i * 16 + ln) * BK + swq * 8);
        #pragma unroll
        for (int j = 0; j < 2; ++j)
            bf[j] = *(const short8*)(Bb + (wn * 32 + j * 16 + ln) * BK + swq * 8);
        #pragma unroll
        for (int i = 0; i < 4; ++i)
            #pragma unroll
            for (int j = 0; j < 2; ++j)
                acc[i][j] = __builtin_amdgcn_mfma_f32_16x16x32_bf16(af[i], bf[j], acc[i][j], 0, 0, 0);
    }
    #pragma unroll
    for (int i = 0; i < 4; ++i) {
        #pragma unroll
        for (int r = 0; r < 4; ++r) {
            int row = m0 + wm * 64 + i * 16 + quad * 4 + r;
            unsigned short* erow = ebuf + ((size_t)e * CBUF + row) * DIM + n0 + wn * 32 + ln;
            #pragma unroll
            for (int j = 0; j < 2; ++j)
                erow[j * 16] = f2bf(acc[i][j][r]);
        }
    }
}

// ---------------- combine: out[t] = sum_k w[t,k] * ebuf[smap[t,k]] ----------------
__global__ __launch_bounds__(256)
void combine_k(const unsigned short* __restrict__ ebuf, const int* __restrict__ smap,
               const float* __restrict__ rwt, float* __restrict__ out) {
    int t = blockIdx.x * 2 + (threadIdx.x >> 7);
    int c = (threadIdx.x & 127) * 8;
    float acc[8];
    #pragma unroll
    for (int j = 0; j < 8; ++j) acc[j] = 0.f;
    #pragma unroll
    for (int k = 0; k < 2; ++k) {
        int sm = smap[t * 2 + k];
        if (sm >= 0) {
            float wgt = rwt[t * 2 + k];
            uint4 rv = *(const uint4*)(ebuf + (size_t)sm * DIM + c);
            unsigned int d[4] = {rv.x, rv.y, rv.z, rv.w};
            #pragma unroll
            for (int q = 0; q < 4; ++q) {
                acc[q * 2 + 0] += wgt * __uint_as_float(d[q] << 16);
                acc[q * 2 + 1] += wgt * __uint_as_float(d[q] & 0xffff0000u);
            }
        }
    }
    float4 o0 = {acc[0], acc[1], acc[2], acc[3]};
    float4 o1 = {acc[4], acc[5], acc[6], acc[7]};
    float* orow = out + (size_t)t * DIM + c;
    *(float4*)(orow + 0) = o0;
    *(float4*)(orow + 4) = o1;
}

extern "C" void kernel_launch(void* const* d_in, const int* in_sizes, int n_in,
                              void* d_out, int out_size, void* d_ws, size_t ws_size,
                              hipStream_t stream) {
    const float* x  = (const float*)d_in[0];   // (2,2048,1024)
    const float* rw = (const float*)d_in[1];   // (1024,16)
    const float* gw = (const float*)d_in[2];   // (16,1024,1024) [e][d][h]
    const float* uw = (const float*)d_in[3];   // (16,1024,1024) [e][d][h]
    const float* dw = (const float*)d_in[4];   // (16,1024,1024) [e][h][d]
    float* out = (float*)d_out;

    char* ws = (char*)d_ws;
    size_t off = 0;
    auto alloc = [&](size_t bytes) { void* p = ws + off; off += (bytes + 255) & ~(size_t)255; return p; };
    unsigned short* xb  = (unsigned short*)alloc((size_t)(T_TOK + 1) * DIM * 2);
    unsigned short* gt  = (unsigned short*)alloc((size_t)NE * DIM * HID * 2);  // [e][h][d]
    unsigned short* ut  = (unsigned short*)alloc((size_t)NE * DIM * HID * 2);  // [e][h][d]
    unsigned short* dtw = (unsigned short*)alloc((size_t)NE * DIM * HID * 2);  // [e][d][h]
    unsigned short* hid = (unsigned short*)alloc((size_t)NE * CBUF * HID * 2);
    int*   disp   = (int*)alloc((size_t)NE * CBUF * 4);
    int*   smap   = (int*)alloc((size_t)T_TOK * 2 * 4);
    int*   tmeta  = (int*)alloc((4 + MAXTILE) * 4);
    int*   re     = (int*)alloc((size_t)T_TOK * 2 * 4);
    float* rwt    = (float*)alloc((size_t)T_TOK * 2 * 4);
    // ebuf (40 MB) aliases gt+ut (64 MB): gate/up weights are dead after gemm1.
    unsigned short* ebuf = gt;
    (void)ws_size; (void)in_sizes; (void)n_in;

    convert_x_k<<<T_TOK + 1, 256, 0, stream>>>(x, xb);
    transpose_cvt_k<<<dim3(16, 16, 48), 256, 0, stream>>>(gw, uw, dw, gt, ut, dtw);
    router_k<<<T_TOK, 64, 0, stream>>>(x, rw, re, rwt);
    build_dispatch_k<<<1, 1024, 0, stream>>>(re, rwt, disp, smap, tmeta);
    gemm1_k<<<dim3(HID / BN, MAXTILE), 256, 0, stream>>>(xb, gt, ut, disp, tmeta, hid);
    gemm2_k<<<dim3(DIM / BN, MAXTILE), 256, 0, stream>>>(hid, dtw, tmeta, ebuf);
    combine_k<<<T_TOK / 2, 256, 0, stream>>>(ebuf, smap, rwt, out);
}